// Round 4
// baseline (133.979 us; speedup 1.0000x reference)
//
#include <hip/hip_runtime.h>
#include <hip/hip_cooperative_groups.h>
#include <math.h>

namespace cg = cooperative_groups;

// DecoderGATLayer — algebraically simplified, single cooperative kernel.
// S=192, B=2, E=512, H=2, D=256, BH=4. All f32.
// Dead inputs: ex_entity, ex_relation, Wxe, Wxr (reference deletes `we`).
// score[bh,t,s] = A[s&3][i] + B[t&3][s] + C[s&3][i] - C[s&3][j] + ba
//   i = bh*48 + (t>>2), j = (t&3)*48 + (s>>2)

#define SS 192
// workspace float offsets
#define QO 0
#define KO 98304
#define VO 196608
#define EO 294912
#define TO 393216     // 12*192 = 2304 floats
#define OO 395520     // attn out, [384][512] row-major (row = 2t+b, col = h*256+d)

#define KC 64
#define LST 34        // LDS k-major stride (even -> float2 aligned; <=2-way banks)

// ---- tiled GEMM core: C[r][d] = sum_k A[r][k] * W[d][k] + bias[d]
// 32x32 output tile, 2x2 per thread, K=512, 256 threads.
__device__ __forceinline__ void gemm_tile(
    const float* __restrict__ A, const float* __restrict__ W,
    const float* __restrict__ bias, float* __restrict__ C, int ldC,
    int r0, int d0, float* __restrict__ AL, float* __restrict__ WL)
{
    int t  = threadIdx.x;
    int td = t & 15;          // d pair index
    int tr = t >> 4;          // r pair index (0..15)
    int lrow = t >> 4;        // staging row (0..15)
    int lf4  = t & 15;        // staging float4 col (0..15)
    float acc00 = 0.f, acc01 = 0.f, acc10 = 0.f, acc11 = 0.f;

    for (int kc = 0; kc < 512; kc += KC) {
        __syncthreads();
        #pragma unroll
        for (int i = 0; i < 2; i++) {
            int x = lrow + 16 * i;                       // 0..31
            float4 av = *(const float4*)(A + (size_t)(r0 + x) * 512 + kc + lf4 * 4);
            float4 wv = *(const float4*)(W + (size_t)(d0 + x) * 512 + kc + lf4 * 4);
            int kb = lf4 * 4;
            AL[(kb + 0) * LST + x] = av.x; AL[(kb + 1) * LST + x] = av.y;
            AL[(kb + 2) * LST + x] = av.z; AL[(kb + 3) * LST + x] = av.w;
            WL[(kb + 0) * LST + x] = wv.x; WL[(kb + 1) * LST + x] = wv.y;
            WL[(kb + 2) * LST + x] = wv.z; WL[(kb + 3) * LST + x] = wv.w;
        }
        __syncthreads();
        #pragma unroll 16
        for (int k = 0; k < KC; k++) {
            float2 w2 = *(const float2*)(WL + k * LST + td * 2);
            float2 a2 = *(const float2*)(AL + k * LST + tr * 2);
            acc00 += a2.x * w2.x; acc01 += a2.x * w2.y;
            acc10 += a2.y * w2.x; acc11 += a2.y * w2.y;
        }
    }
    int d = d0 + td * 2, r = r0 + tr * 2;
    float b0 = bias[d], b1 = bias[d + 1];
    C[(size_t)r * ldC + d]           = acc00 + b0;
    C[(size_t)r * ldC + d + 1]       = acc01 + b1;
    C[(size_t)(r + 1) * ldC + d]     = acc10 + b0;
    C[(size_t)(r + 1) * ldC + d + 1] = acc11 + b1;
}

__global__ __launch_bounds__(256) void k_fused(
    const float* __restrict__ query, const float* __restrict__ entity,
    const float* __restrict__ Wq, const float* __restrict__ bq,
    const float* __restrict__ Wk, const float* __restrict__ bk,
    const float* __restrict__ Wv, const float* __restrict__ bv,
    const float* __restrict__ We, const float* __restrict__ be,
    const float* __restrict__ Wa, const float* __restrict__ ba_p,
    const float* __restrict__ Wo, const float* __restrict__ bo,
    float* __restrict__ ws, float* __restrict__ out)
{
    cg::grid_group grid = cg::this_grid();
    __shared__ float lds[2 * KC * LST];   // 17408 B, reused by all phases
    int blk = blockIdx.x;                 // 0..191
    int tid = threadIdx.x;

    // ===== phase 1: four projections (384 tiles, 2 per block) =====
    #pragma unroll 1
    for (int ti = 0; ti < 2; ti++) {
        int bi  = blk * 2 + ti;           // 0..383
        int m   = bi / 96;
        int rem = bi % 96;
        int d0  = (rem & 7) * 32;
        int r0  = (rem >> 3) * 32;
        const float* src; const float* W; const float* bias; float* dst;
        if      (m == 0) { src = query;  W = Wq; bias = bq; dst = ws + QO; }
        else if (m == 1) { src = query;  W = Wk; bias = bk; dst = ws + KO; }
        else if (m == 2) { src = query;  W = Wv; bias = bv; dst = ws + VO; }
        else             { src = entity; W = We; bias = be; dst = ws + EO; }
        gemm_tile(src, W, bias, dst, 256, r0, d0, lds, lds + KC * LST);
    }
    grid.sync();

    // ===== phase 2: score tables (2304 rows over 768 waves, 3 each) =====
    {
        int gwave = blk * 4 + (tid >> 6);   // 0..767
        int lane  = tid & 63;
        const float* q = ws + QO;
        const float* k = ws + KO;
        const float* e = ws + EO;
        #pragma unroll 1
        for (int r = 0; r < 3; r++) {
            int w   = gwave * 3 + r;        // 0..2303
            int tab = w / SS;
            int idx = w % SS;
            const float* src; const float* wt;
            if (tab < 4) {
                int b = tab >> 1, h = tab & 1;
                src = (h ? e : q) + (size_t)(idx * 2 + b) * 256;  wt = Wa;
            } else if (tab < 8) {
                int p = tab - 4; int b = p >> 1, h = p & 1;
                src = (h ? e : k) + (size_t)(idx * 2 + b) * 256;  wt = Wa + 256;
            } else {
                int m = tab - 8;
                src = entity + (size_t)(idx * 2 + (m >> 1)) * 512 + (m & 1) * 256;
                wt  = Wa + 512;
            }
            float p = 0.f;
            #pragma unroll
            for (int i = 0; i < 4; i++) p += src[lane + 64 * i] * wt[lane + 64 * i];
            #pragma unroll
            for (int off = 32; off >= 1; off >>= 1) p += __shfl_xor(p, off, 64);
            if (lane == 0) ws[TO + tab * SS + idx] = p;
        }
    }
    grid.sync();

    // ===== phase 3: attention (4 t per block, wave-private softmax) =====
    {
        float (*sp)[SS] = (float (*)[SS])lds;   // 3 KB, aliases GEMM buffer
        int bh = blk & 3;
        int tg = blk >> 2;          // 0..47
        int b = bh >> 1, h = bh & 1;
        const float* T = ws + TO;
        float ba = ba_p[0];
        int wave = tid >> 6, lane = tid & 63;
        int t = tg * 4 + wave;
        int i_idx = bh * 48 + (t >> 2);
        int tmod  = t & 3;

        float sc[3];
        float mx = -1e30f;
        #pragma unroll
        for (int i = 0; i < 3; i++) {
            int s_ = lane + 64 * i;
            int m  = s_ & 3;
            int j  = tmod * 48 + (s_ >> 2);
            float x = T[m * SS + i_idx] + T[(4 + tmod) * SS + s_]
                    + T[(8 + m) * SS + i_idx] - T[(8 + m) * SS + j] + ba;
            x = (x >= 0.f) ? x : 0.01f * x;    // leaky_relu
            sc[i] = x;
            mx = fmaxf(mx, x);
        }
        #pragma unroll
        for (int o = 32; o >= 1; o >>= 1) mx = fmaxf(mx, __shfl_xor(mx, o, 64));
        float sum = 0.f;
        #pragma unroll
        for (int i = 0; i < 3; i++) { sc[i] = __expf(sc[i] - mx); sum += sc[i]; }
        #pragma unroll
        for (int o = 32; o >= 1; o >>= 1) sum += __shfl_xor(sum, o, 64);
        float inv = 1.f / sum;
        __syncthreads();   // ensure phase-1 LDS use is fully done before overwrite
        #pragma unroll
        for (int i = 0; i < 3; i++) sp[wave][lane + 64 * i] = sc[i] * inv;
        __syncthreads();

        const float* base = (h ? ws + EO : ws + VO) + b * 256 + tid;
        float a0 = 0.f, a1 = 0.f, a2 = 0.f, a3 = 0.f;
        #pragma unroll 4
        for (int s = 0; s < SS; s++) {
            float v = base[(size_t)s * 512];
            a0 += sp[0][s] * v; a1 += sp[1][s] * v;
            a2 += sp[2][s] * v; a3 += sp[3][s] * v;
        }
        size_t colbase = (size_t)h * 256 + tid;
        int t0 = tg * 4;
        ws[OO + (size_t)((t0 + 0) * 2 + b) * 512 + colbase] = a0;
        ws[OO + (size_t)((t0 + 1) * 2 + b) * 512 + colbase] = a1;
        ws[OO + (size_t)((t0 + 2) * 2 + b) * 512 + colbase] = a2;
        ws[OO + (size_t)((t0 + 3) * 2 + b) * 512 + colbase] = a3;
    }
    grid.sync();

    // ===== phase 4: output fc (192 tiles, 1 per block) =====
    {
        int d0 = (blk & 15) * 32;
        int r0 = (blk >> 4) * 32;
        gemm_tile(ws + OO, Wo, bo, out, 512, r0, d0, lds, lds + KC * LST);
    }
}

extern "C" void kernel_launch(void* const* d_in, const int* in_sizes, int n_in,
                              void* d_out, int out_size, void* d_ws, size_t ws_size,
                              hipStream_t stream) {
    const float* query  = (const float*)d_in[0];
    const float* entity = (const float*)d_in[1];
    // d_in[2] ex_entity, d_in[3] ex_relation: dead
    const float* Wq = (const float*)d_in[4];  const float* bq = (const float*)d_in[5];
    const float* Wk = (const float*)d_in[6];  const float* bk = (const float*)d_in[7];
    const float* Wv = (const float*)d_in[8];  const float* bv = (const float*)d_in[9];
    const float* We = (const float*)d_in[10]; const float* be = (const float*)d_in[11];
    // d_in[12..15] dead
    const float* Wa = (const float*)d_in[16]; const float* ba = (const float*)d_in[17];
    const float* Wo = (const float*)d_in[18]; const float* bo = (const float*)d_in[19];
    float* ws  = (float*)d_ws;
    float* out = (float*)d_out;

    void* args[] = {
        (void*)&query, (void*)&entity,
        (void*)&Wq, (void*)&bq, (void*)&Wk, (void*)&bk,
        (void*)&Wv, (void*)&bv, (void*)&We, (void*)&be,
        (void*)&Wa, (void*)&ba, (void*)&Wo, (void*)&bo,
        (void*)&ws, (void*)&out
    };
    hipLaunchCooperativeKernel((const void*)k_fused, dim3(192), dim3(256),
                               args, 0, stream);
}

// Round 5
// 120.909 us; speedup vs baseline: 1.1081x; 1.1081x over previous
//
#include <hip/hip_runtime.h>
#include <math.h>

// DecoderGATLayer — algebraically simplified. S=192, B=2, E=512, H=2, D=256, BH=4. f32.
// Dead inputs: ex_entity, ex_relation, Wxe, Wxr (reference deletes `we`).
// score[bh,t,s] = A[s&3][i] + B[t&3][s] + C[s&3][i] - C[s&3][j] + ba
//   i = bh*48 + (t>>2), j = (t&3)*48 + (s>>2)
//
// GEMM strategy: NO LDS. A rows are block-uniform -> scalar-cache broadcast loads.
// W pre-transposed once into WT4[k4*D + d] (float4 of 4 consecutive k for col d)
// so the W stream is a perfectly coalesced 16B/lane vector load.

#define SS 192
// workspace float offsets
#define QO 0
#define KO 98304
#define VO 196608
#define EO 294912
#define TO 393216          // 12*192 = 2304
#define OO 395520          // attn out [384][512], row = 2t+b, col = h*256+d
#define WTQ 592128         // 131072 floats each (WT for 256-col mats)
#define WTK 723200
#define WTV 854272
#define WTE 985344
#define WTO 1116416        // 262144 floats
// total ws use: 1378560 floats = 5.26 MB

// ---- transpose: WT4[k4*D + d] = W4[d*128 + k4]  (W is [D][512] row-major)
// grid 768 x 256 threads; one float4 per thread.
__global__ __launch_bounds__(256) void k_trans(
    const float* __restrict__ Wq, const float* __restrict__ Wk,
    const float* __restrict__ Wv, const float* __restrict__ We,
    const float* __restrict__ Wo, float* __restrict__ ws)
{
    int o = blockIdx.x * 256 + threadIdx.x;   // 0..196607
    const float4* src; float4* dst; int idx; int D;
    if (o < 98304) {
        if (o < 32768)      { src = (const float4*)Wq; dst = (float4*)(ws + WTQ); idx = o; }
        else if (o < 65536) { src = (const float4*)Wk; dst = (float4*)(ws + WTK); idx = o - 32768; }
        else                { src = (const float4*)Wv; dst = (float4*)(ws + WTV); idx = o - 65536; }
        D = 256;
    } else if (o < 131072) { src = (const float4*)We; dst = (float4*)(ws + WTE); idx = o - 98304; D = 256; }
    else                   { src = (const float4*)Wo; dst = (float4*)(ws + WTO); idx = o - 131072; D = 512; }
    int k4 = (D == 256) ? (idx >> 8) : (idx >> 9);
    int d  = (D == 256) ? (idx & 255) : (idx & 511);
    dst[idx] = src[d * 128 + k4];
}

// ---- projections: 4 mats x 48 row-groups = 192 blocks, 8 rows each, 256 cols.
__global__ __launch_bounds__(256) void k_proj(
    const float* __restrict__ query, const float* __restrict__ entity,
    const float* __restrict__ bq, const float* __restrict__ bk,
    const float* __restrict__ bv, const float* __restrict__ be,
    float* __restrict__ ws)
{
    int blk = blockIdx.x;
    int m   = blk / 48;
    int r0  = (blk % 48) * 8;
    int d   = threadIdx.x;
    const float* A; const float* bias; const float4* WT; float* dst;
    if      (m == 0) { A = query;  bias = bq; WT = (const float4*)(ws + WTQ); dst = ws + QO; }
    else if (m == 1) { A = query;  bias = bk; WT = (const float4*)(ws + WTK); dst = ws + KO; }
    else if (m == 2) { A = query;  bias = bv; WT = (const float4*)(ws + WTV); dst = ws + VO; }
    else             { A = entity; bias = be; WT = (const float4*)(ws + WTE); dst = ws + EO; }
    const float4* A4 = (const float4*)A;     // [384][128]

    float acc[8];
    #pragma unroll
    for (int r = 0; r < 8; r++) acc[r] = 0.f;

    #pragma unroll 4
    for (int k4 = 0; k4 < 128; k4++) {
        float4 w = WT[k4 * 256 + d];
        #pragma unroll
        for (int r = 0; r < 8; r++) {
            float4 a = A4[(r0 + r) * 128 + k4];   // block-uniform -> scalar loads
            acc[r] += a.x * w.x + a.y * w.y + a.z * w.z + a.w * w.w;
        }
    }
    float bd = bias[d];
    #pragma unroll
    for (int r = 0; r < 8; r++)
        dst[(size_t)(r0 + r) * 256 + d] = acc[r] + bd;
}

// ---- score tables (12 x 192 rows over 576 blocks x 4 waves)
__global__ __launch_bounds__(256) void k_tabs(
    const float* __restrict__ entity, const float* __restrict__ Wa,
    float* __restrict__ ws)
{
    int w    = blockIdx.x * 4 + (threadIdx.x >> 6);  // 0..2303
    int lane = threadIdx.x & 63;
    int tab  = w / SS;
    int idx  = w % SS;
    const float* q = ws + QO;
    const float* k = ws + KO;
    const float* e = ws + EO;
    const float* src; const float* wt;
    if (tab < 4) {
        int b = tab >> 1, h = tab & 1;
        src = (h ? e : q) + (size_t)(idx * 2 + b) * 256;  wt = Wa;
    } else if (tab < 8) {
        int p = tab - 4; int b = p >> 1, h = p & 1;
        src = (h ? e : k) + (size_t)(idx * 2 + b) * 256;  wt = Wa + 256;
    } else {
        int m = tab - 8;
        src = entity + (size_t)(idx * 2 + (m >> 1)) * 512 + (m & 1) * 256;  wt = Wa + 512;
    }
    float p = 0.f;
    #pragma unroll
    for (int i = 0; i < 4; i++) p += src[lane + 64 * i] * wt[lane + 64 * i];
    #pragma unroll
    for (int off = 32; off >= 1; off >>= 1) p += __shfl_xor(p, off, 64);
    if (lane == 0) ws[TO + tab * SS + idx] = p;
}

// ---- attention: 4 t per block (one per wave), wave-private softmax. 192 blocks.
__global__ __launch_bounds__(256) void k_attn(
    const float* __restrict__ ba_p, float* __restrict__ ws)
{
    __shared__ float sp[4][SS];
    int bi = blockIdx.x;
    int bh = bi & 3;
    int tg = bi >> 2;
    int b = bh >> 1, h = bh & 1;
    const float* T = ws + TO;
    float ba = ba_p[0];
    int tid  = threadIdx.x;
    int wave = tid >> 6, lane = tid & 63;
    int t = tg * 4 + wave;
    int i_idx = bh * 48 + (t >> 2);
    int tmod  = t & 3;

    float sc[3];
    float mx = -1e30f;
    #pragma unroll
    for (int i = 0; i < 3; i++) {
        int s_ = lane + 64 * i;
        int m  = s_ & 3;
        int j  = tmod * 48 + (s_ >> 2);
        float x = T[m * SS + i_idx] + T[(4 + tmod) * SS + s_]
                + T[(8 + m) * SS + i_idx] - T[(8 + m) * SS + j] + ba;
        x = (x >= 0.f) ? x : 0.01f * x;    // leaky_relu
        sc[i] = x;
        mx = fmaxf(mx, x);
    }
    #pragma unroll
    for (int o = 32; o >= 1; o >>= 1) mx = fmaxf(mx, __shfl_xor(mx, o, 64));
    float sum = 0.f;
    #pragma unroll
    for (int i = 0; i < 3; i++) { sc[i] = __expf(sc[i] - mx); sum += sc[i]; }
    #pragma unroll
    for (int o = 32; o >= 1; o >>= 1) sum += __shfl_xor(sum, o, 64);
    float inv = 1.f / sum;
    #pragma unroll
    for (int i = 0; i < 3; i++) sp[wave][lane + 64 * i] = sc[i] * inv;
    __syncthreads();

    const float* base = (h ? ws + EO : ws + VO) + b * 256 + tid;
    float a0 = 0.f, a1 = 0.f, a2 = 0.f, a3 = 0.f;
    #pragma unroll 4
    for (int s = 0; s < SS; s++) {
        float v = base[(size_t)s * 512];
        a0 += sp[0][s] * v; a1 += sp[1][s] * v;
        a2 += sp[2][s] * v; a3 += sp[3][s] * v;
    }
    size_t colbase = (size_t)h * 256 + tid;
    int t0 = tg * 4;
    ws[OO + (size_t)((t0 + 0) * 2 + b) * 512 + colbase] = a0;
    ws[OO + (size_t)((t0 + 1) * 2 + b) * 512 + colbase] = a1;
    ws[OO + (size_t)((t0 + 2) * 2 + b) * 512 + colbase] = a2;
    ws[OO + (size_t)((t0 + 3) * 2 + b) * 512 + colbase] = a3;
}

// ---- output fc: A = ws+OO [384][512], WT = WTO. 96 blocks: 48 rgroups x 2 col-halves.
__global__ __launch_bounds__(256) void k_out(
    const float* __restrict__ bo, const float* __restrict__ ws,
    float* __restrict__ out)
{
    int blk = blockIdx.x;
    int r0  = (blk % 48) * 8;
    int col = (blk / 48) * 256 + threadIdx.x;
    const float4* A4  = (const float4*)(ws + OO);    // [384][128]
    const float4* WT  = (const float4*)(ws + WTO);   // [128][512]

    float acc[8];
    #pragma unroll
    for (int r = 0; r < 8; r++) acc[r] = 0.f;

    #pragma unroll 4
    for (int k4 = 0; k4 < 128; k4++) {
        float4 w = WT[k4 * 512 + col];
        #pragma unroll
        for (int r = 0; r < 8; r++) {
            float4 a = A4[(r0 + r) * 128 + k4];   // block-uniform -> scalar loads
            acc[r] += a.x * w.x + a.y * w.y + a.z * w.z + a.w * w.w;
        }
    }
    float bd = bo[col];
    #pragma unroll
    for (int r = 0; r < 8; r++)
        out[(size_t)(r0 + r) * 512 + col] = acc[r] + bd;
}

extern "C" void kernel_launch(void* const* d_in, const int* in_sizes, int n_in,
                              void* d_out, int out_size, void* d_ws, size_t ws_size,
                              hipStream_t stream) {
    const float* query  = (const float*)d_in[0];
    const float* entity = (const float*)d_in[1];
    // d_in[2] ex_entity, d_in[3] ex_relation: dead
    const float* Wq = (const float*)d_in[4];  const float* bq = (const float*)d_in[5];
    const float* Wk = (const float*)d_in[6];  const float* bk = (const float*)d_in[7];
    const float* Wv = (const float*)d_in[8];  const float* bv = (const float*)d_in[9];
    const float* We = (const float*)d_in[10]; const float* be = (const float*)d_in[11];
    // d_in[12..15] dead
    const float* Wa = (const float*)d_in[16]; const float* ba = (const float*)d_in[17];
    const float* Wo = (const float*)d_in[18]; const float* bo = (const float*)d_in[19];
    float* ws  = (float*)d_ws;
    float* out = (float*)d_out;

    hipLaunchKernelGGL(k_trans, dim3(768), dim3(256), 0, stream, Wq, Wk, Wv, We, Wo, ws);
    hipLaunchKernelGGL(k_proj,  dim3(192), dim3(256), 0, stream,
                       query, entity, bq, bk, bv, be, ws);
    hipLaunchKernelGGL(k_tabs,  dim3(576), dim3(256), 0, stream, entity, Wa, ws);
    hipLaunchKernelGGL(k_attn,  dim3(192), dim3(256), 0, stream, ba, ws);
    hipLaunchKernelGGL(k_out,   dim3(96),  dim3(256), 0, stream, bo, ws, out);
}

// Round 6
// 67.184 us; speedup vs baseline: 1.9942x; 1.7997x over previous
//
#include <hip/hip_runtime.h>
#include <math.h>

// DecoderGATLayer — algebraically simplified. S=192, B=2, E=512, H=2, D=256, BH=4. f32.
// Dead inputs: ex_entity, ex_relation, Wxe, Wxr (reference deletes `we`).
// score[bh,t,s] = A[s&3][i] + B[t&3][s] + C[s&3][i] - C[s&3][j] + ba
//   i = bh*48 + (t>>2), j = (t&3)*48 + (s>>2)
//
// GEMMs: no-LDS-staging dot kernels; A rows via scalar-uniform loads, W via
// pre-transposed WT (coalesced float4). Latency hidden by split-k x4 inside
// 1024-thread blocks (12 waves/CU) with LDS partial reduce.

#define SS 192
// workspace float offsets
#define QO 0
#define KO 98304
#define VO 196608
#define EO 294912
#define TO 393216          // 12*192 = 2304
#define OO 395520          // attn out [384][512], row = 2t+b, col = h*256+d
#define WTQ 592128         // 131072 floats each (WT for 256-col mats)
#define WTK 723200
#define WTV 854272
#define WTE 985344
#define WTO 1116416        // 262144 floats
// total ws use: 1378560 floats = 5.26 MB (known-safe footprint)

// ---- transpose: WT4[k4*D + d] = W4[d*128 + k4]. Coalesced reads, scattered writes.
__global__ __launch_bounds__(256) void k_trans(
    const float* __restrict__ Wq, const float* __restrict__ Wk,
    const float* __restrict__ Wv, const float* __restrict__ We,
    const float* __restrict__ Wo, float* __restrict__ ws)
{
    int o = blockIdx.x * 256 + threadIdx.x;   // 0..196607
    const float4* src; float4* dst; int idx; int D;
    if (o < 98304) {
        if (o < 32768)      { src = (const float4*)Wq; dst = (float4*)(ws + WTQ); idx = o; }
        else if (o < 65536) { src = (const float4*)Wk; dst = (float4*)(ws + WTK); idx = o - 32768; }
        else                { src = (const float4*)Wv; dst = (float4*)(ws + WTV); idx = o - 65536; }
        D = 256;
    } else if (o < 131072) { src = (const float4*)We; dst = (float4*)(ws + WTE); idx = o - 98304; D = 256; }
    else                   { src = (const float4*)Wo; dst = (float4*)(ws + WTO); idx = o - 131072; D = 512; }
    // coalesced read: consecutive idx walk src rows; scatter write into [k4][d]
    int d  = (D == 256) ? (idx >> 7) : (idx >> 7);   // src row = idx/128
    int k4 = idx & 127;
    dst[k4 * D + d] = src[idx];
}

// ---- projections: 192 blocks x 1024 thr. Block = (mat, 8-row group).
// Threads: chunk = tid>>8 (k-split x4), d = tid&255. LDS partial reduce.
__global__ __launch_bounds__(1024, 4) void k_proj(
    const float* __restrict__ query, const float* __restrict__ entity,
    const float* __restrict__ bq, const float* __restrict__ bk,
    const float* __restrict__ bv, const float* __restrict__ be,
    float* __restrict__ ws)
{
    __shared__ float part[4 * 8 * 256];      // 32 KB
    int blk = blockIdx.x;
    int m   = blk / 48;
    int r0  = (blk % 48) * 8;
    int tid = threadIdx.x;
    int chunk = __builtin_amdgcn_readfirstlane(tid >> 8);  // wave-uniform
    int d   = tid & 255;
    const float* A; const float* bias; const float4* WT; float* dst;
    if      (m == 0) { A = query;  bias = bq; WT = (const float4*)(ws + WTQ); dst = ws + QO; }
    else if (m == 1) { A = query;  bias = bk; WT = (const float4*)(ws + WTK); dst = ws + KO; }
    else if (m == 2) { A = query;  bias = bv; WT = (const float4*)(ws + WTV); dst = ws + VO; }
    else             { A = entity; bias = be; WT = (const float4*)(ws + WTE); dst = ws + EO; }
    const float4* A4 = (const float4*)A;     // [384][128]

    float acc[8];
    #pragma unroll
    for (int r = 0; r < 8; r++) acc[r] = 0.f;

    int k4b = chunk * 32;
    #pragma unroll 4
    for (int i = 0; i < 32; i++) {
        int k4 = k4b + i;
        float4 w = WT[k4 * 256 + d];
        #pragma unroll
        for (int r = 0; r < 8; r++) {
            float4 a = A4[(r0 + r) * 128 + k4];   // wave-uniform -> scalar loads
            acc[r] += a.x * w.x + a.y * w.y + a.z * w.z + a.w * w.w;
        }
    }
    #pragma unroll
    for (int r = 0; r < 8; r++) part[(chunk * 8 + r) * 256 + d] = acc[r];
    __syncthreads();
    // final reduce: 2048 outputs, 1024 threads -> 2 each
    #pragma unroll
    for (int o = 0; o < 2; o++) {
        int idx = tid + o * 1024;          // r*256 + d
        int rr  = idx >> 8, dd = idx & 255;
        float v = part[idx] + part[2048 + idx] + part[4096 + idx] + part[6144 + idx];
        dst[(size_t)(r0 + rr) * 256 + dd] = v + bias[dd];
    }
}

// ---- score tables (12 x 192 rows over 576 blocks x 4 waves)
__global__ __launch_bounds__(256) void k_tabs(
    const float* __restrict__ entity, const float* __restrict__ Wa,
    float* __restrict__ ws)
{
    int w    = blockIdx.x * 4 + (threadIdx.x >> 6);  // 0..2303
    int lane = threadIdx.x & 63;
    int tab  = w / SS;
    int idx  = w % SS;
    const float* q = ws + QO;
    const float* k = ws + KO;
    const float* e = ws + EO;
    const float* src; const float* wt;
    if (tab < 4) {
        int b = tab >> 1, h = tab & 1;
        src = (h ? e : q) + (size_t)(idx * 2 + b) * 256;  wt = Wa;
    } else if (tab < 8) {
        int p = tab - 4; int b = p >> 1, h = p & 1;
        src = (h ? e : k) + (size_t)(idx * 2 + b) * 256;  wt = Wa + 256;
    } else {
        int m = tab - 8;
        src = entity + (size_t)(idx * 2 + (m >> 1)) * 512 + (m & 1) * 256;  wt = Wa + 512;
    }
    float p = 0.f;
    #pragma unroll
    for (int i = 0; i < 4; i++) p += src[lane + 64 * i] * wt[lane + 64 * i];
    #pragma unroll
    for (int off = 32; off >= 1; off >>= 1) p += __shfl_xor(p, off, 64);
    if (lane == 0) ws[TO + tab * SS + idx] = p;
}

// ---- attention: 4 t per block (one per wave), wave-private softmax. 192 blocks.
__global__ __launch_bounds__(256) void k_attn(
    const float* __restrict__ ba_p, float* __restrict__ ws)
{
    __shared__ float sp[4][SS];
    int bi = blockIdx.x;
    int bh = bi & 3;
    int tg = bi >> 2;
    int b = bh >> 1, h = bh & 1;
    const float* T = ws + TO;
    float ba = ba_p[0];
    int tid  = threadIdx.x;
    int wave = tid >> 6, lane = tid & 63;
    int t = tg * 4 + wave;
    int i_idx = bh * 48 + (t >> 2);
    int tmod  = t & 3;

    float sc[3];
    float mx = -1e30f;
    #pragma unroll
    for (int i = 0; i < 3; i++) {
        int s_ = lane + 64 * i;
        int m  = s_ & 3;
        int j  = tmod * 48 + (s_ >> 2);
        float x = T[m * SS + i_idx] + T[(4 + tmod) * SS + s_]
                + T[(8 + m) * SS + i_idx] - T[(8 + m) * SS + j] + ba;
        x = (x >= 0.f) ? x : 0.01f * x;    // leaky_relu
        sc[i] = x;
        mx = fmaxf(mx, x);
    }
    #pragma unroll
    for (int o = 32; o >= 1; o >>= 1) mx = fmaxf(mx, __shfl_xor(mx, o, 64));
    float sum = 0.f;
    #pragma unroll
    for (int i = 0; i < 3; i++) { sc[i] = __expf(sc[i] - mx); sum += sc[i]; }
    #pragma unroll
    for (int o = 32; o >= 1; o >>= 1) sum += __shfl_xor(sum, o, 64);
    float inv = 1.f / sum;
    #pragma unroll
    for (int i = 0; i < 3; i++) sp[wave][lane + 64 * i] = sc[i] * inv;
    __syncthreads();

    const float* base = (h ? ws + EO : ws + VO) + b * 256 + tid;
    float a0 = 0.f, a1 = 0.f, a2 = 0.f, a3 = 0.f;
    #pragma unroll 4
    for (int s = 0; s < SS; s++) {
        float v = base[(size_t)s * 512];
        a0 += sp[0][s] * v; a1 += sp[1][s] * v;
        a2 += sp[2][s] * v; a3 += sp[3][s] * v;
    }
    size_t colbase = (size_t)h * 256 + tid;
    int t0 = tg * 4;
    ws[OO + (size_t)((t0 + 0) * 2 + b) * 512 + colbase] = a0;
    ws[OO + (size_t)((t0 + 1) * 2 + b) * 512 + colbase] = a1;
    ws[OO + (size_t)((t0 + 2) * 2 + b) * 512 + colbase] = a2;
    ws[OO + (size_t)((t0 + 3) * 2 + b) * 512 + colbase] = a3;
}

// ---- output fc: 192 blocks x 1024 thr. Block = (4-row group rg, col half cg).
// chunk = tid>>8 (k-split x4), col = cg*256 + (tid&255). LDS partial reduce.
__global__ __launch_bounds__(1024, 4) void k_out(
    const float* __restrict__ bo, const float* __restrict__ ws,
    float* __restrict__ out)
{
    __shared__ float part[4 * 4 * 256];      // 16 KB
    int blk = blockIdx.x;
    int rg  = blk >> 1;                      // 0..95
    int cg  = blk & 1;
    int r0  = rg * 4;
    int tid = threadIdx.x;
    int chunk = __builtin_amdgcn_readfirstlane(tid >> 8);
    int col = cg * 256 + (tid & 255);
    const float4* A4 = (const float4*)(ws + OO);    // [384][128]
    const float4* WT = (const float4*)(ws + WTO);   // [128][512]

    float acc[4];
    #pragma unroll
    for (int r = 0; r < 4; r++) acc[r] = 0.f;

    int k4b = chunk * 32;
    #pragma unroll 4
    for (int i = 0; i < 32; i++) {
        int k4 = k4b + i;
        float4 w = WT[k4 * 512 + col];
        #pragma unroll
        for (int r = 0; r < 4; r++) {
            float4 a = A4[(r0 + r) * 128 + k4];   // wave-uniform -> scalar loads
            acc[r] += a.x * w.x + a.y * w.y + a.z * w.z + a.w * w.w;
        }
    }
    int dl = tid & 255;
    #pragma unroll
    for (int r = 0; r < 4; r++) part[(chunk * 4 + r) * 256 + dl] = acc[r];
    __syncthreads();
    // final reduce: 1024 outputs, 1024 threads
    {
        int idx = tid;                      // r*256 + dl
        int rr = idx >> 8, dd = idx & 255;
        float v = part[idx] + part[1024 + idx] + part[2048 + idx] + part[3072 + idx];
        out[(size_t)(r0 + rr) * 512 + cg * 256 + dd] = v + bo[cg * 256 + dd];
    }
}

extern "C" void kernel_launch(void* const* d_in, const int* in_sizes, int n_in,
                              void* d_out, int out_size, void* d_ws, size_t ws_size,
                              hipStream_t stream) {
    const float* query  = (const float*)d_in[0];
    const float* entity = (const float*)d_in[1];
    // d_in[2] ex_entity, d_in[3] ex_relation: dead
    const float* Wq = (const float*)d_in[4];  const float* bq = (const float*)d_in[5];
    const float* Wk = (const float*)d_in[6];  const float* bk = (const float*)d_in[7];
    const float* Wv = (const float*)d_in[8];  const float* bv = (const float*)d_in[9];
    const float* We = (const float*)d_in[10]; const float* be = (const float*)d_in[11];
    // d_in[12..15] dead
    const float* Wa = (const float*)d_in[16]; const float* ba = (const float*)d_in[17];
    const float* Wo = (const float*)d_in[18]; const float* bo = (const float*)d_in[19];
    float* ws  = (float*)d_ws;
    float* out = (float*)d_out;

    hipLaunchKernelGGL(k_trans, dim3(768), dim3(256),  0, stream, Wq, Wk, Wv, We, Wo, ws);
    hipLaunchKernelGGL(k_proj,  dim3(192), dim3(1024), 0, stream,
                       query, entity, bq, bk, bv, be, ws);
    hipLaunchKernelGGL(k_tabs,  dim3(576), dim3(256),  0, stream, entity, Wa, ws);
    hipLaunchKernelGGL(k_attn,  dim3(192), dim3(256),  0, stream, ba, ws);
    hipLaunchKernelGGL(k_out,   dim3(192), dim3(1024), 0, stream, bo, ws, out);
}